// Round 14
// baseline (119.845 us; speedup 1.0000x reference)
//
#include <hip/hip_runtime.h>
#include <cstdint>

// Ball query: B=8, N=4096, radius=0.2, nsample=32. Queries == sources.
// Output int32 (B,N,32): first 32 in-radius indices ascending, padded with
// the first match.
//
// NUMERICS (LOCKED, R8-verified absmax=0): expansion form f32,
//   sq  = (x*x + y*y) + z*z              -- plain, no FMA
//   dot = fma(qz,sz, fma(qy,sy, qx*sx))  -- FMA, K ascending
//   d2  = (sqq + sqs) - (dot + dot)
//   match = d2 < 0.04f
// Inline asm (immune to -ffast-math). DO NOT CHANGE the op sequence.
//
// R14 perf: R8-R13 wall stuck ~36us across 4x occupancy / 3x LDS-read
// variation -> bound by the SERIAL critical path of full-scan waves
// (corner queries with <32 neighbors must scan all 4096; d2 asm blobs are
// opaque ~28cyc units, ~350cyc/round, 64 rounds). Fix: WAVE-PAIR SPLIT --
// even wave scans pts 0..2047, odd wave 2048..4095 for the same 8 queries
// (local exit at 32 is exactly correct per half); merge ballot-words via
// LDS scratch + 1 barrier; even wave emits. Critical path halves.

#define BQ_N   4096
#define BQ_B   8
#define BQ_NS  32
#define BQ_R2  0.04f

__device__ __forceinline__ float sq_plain(float x, float y, float z) {
    float r, t;
    asm("v_mul_f32 %0, %2, %2\n\t"
        "v_mul_f32 %1, %3, %3\n\t"
        "v_add_f32 %0, %0, %1\n\t"
        "v_mul_f32 %1, %4, %4\n\t"
        "v_add_f32 %0, %0, %1"
        : "=&v"(r), "=&v"(t)
        : "v"(x), "v"(y), "v"(z));
    return r;
}

// Query operands in SGPRs (wave-uniform; 1 SGPR per VALU op -- legal).
// Identical opcode sequence to the R8-verified version.
__device__ __forceinline__ float d2_mixed_s(float qx, float qy, float qz,
                                            float sqq,
                                            float sx, float sy, float sz,
                                            float sqs) {
    float r, t;
    asm("v_mul_f32 %0, %2, %5\n\t"     // qx*sx
        "v_fma_f32 %0, %3, %6, %0\n\t" // + qy*sy (fused)
        "v_fma_f32 %0, %4, %7, %0\n\t" // + qz*sz (fused) = dot
        "v_add_f32 %0, %0, %0\n\t"     // 2*dot (exact)
        "v_add_f32 %1, %8, %9\n\t"     // sqq + sqs
        "v_sub_f32 %0, %1, %0"         // d2
        : "=&v"(r), "=&v"(t)
        : "s"(qx), "s"(qy), "s"(qz), "v"(sx), "v"(sy), "v"(sz),
          "s"(sqq), "v"(sqs));
    return r;
}

__device__ __forceinline__ float rfl(float v) {
    return __int_as_float(__builtin_amdgcn_readfirstlane(__float_as_int(v)));
}

__device__ __forceinline__ void emit_query(int* orow, int lane, uint64_t word) {
    const int cnt = __popcll(word);
    int incl = cnt;
    #pragma unroll
    for (int off = 1; off < 64; off <<= 1) {
        const int t = __shfl_up(incl, off);
        if (lane >= off) incl += t;
    }
    const int pre   = incl - cnt;
    const int total = __shfl(incl, 63);

    int first;
    const uint64_t nz = __ballot(word != 0ull);
    if (nz == 0ull) {
        first = BQ_N;   // defensive; self-match makes this unreachable
    } else {
        const int fl = __builtin_ctzll(nz);
        const uint64_t fw = __shfl(word, fl);
        first = (fl << 6) + __builtin_ctzll(fw);
    }

    uint64_t w = word;
    int pos = pre;
    while (w != 0ull && pos < BQ_NS) {
        const int bit = __builtin_ctzll(w);
        orow[pos] = (lane << 6) + bit;
        w &= (w - 1);
        ++pos;
    }
    if (lane >= total && lane < BQ_NS) orow[lane] = first;  // padding
}

__global__ __launch_bounds__(512, 8)
void ball_query_kernel(const float* __restrict__ xyz, int* __restrict__ out)
{
    __shared__ float4 pts[BQ_N];                 // 64 KiB
    __shared__ unsigned long long xw[4][8][32];  // 8 KiB merge scratch

    const int b     = blockIdx.x >> 7;          // 128 blocks per batch
    const int qbase = (blockIdx.x & 127) << 5;  // 32 queries per block
    const float* __restrict__ src = xyz + (size_t)b * BQ_N * 3;
    const int lane = threadIdx.x & 63;
    const int wid  = threadIdx.x >> 6;          // 0..7
    const int pair = wid >> 1;                  // 0..3
    const int half = wid & 1;                   // 0: pts 0..2047, 1: 2048..4095
    int* __restrict__ outb = out + (size_t)(b * BQ_N) * BQ_NS;

    // The pair's 8 queries -> SGPRs.
    float qx[8], qy[8], qz[8], qw[8];
    #pragma unroll
    for (int j = 0; j < 8; ++j) {
        const int m = qbase + (pair << 3) + j;
        const float x = src[3 * m + 0];
        const float y = src[3 * m + 1];
        const float z = src[3 * m + 2];
        const float w = sq_plain(x, y, z);
        qx[j] = rfl(x); qy[j] = rfl(y); qz[j] = rfl(z); qw[j] = rfl(w);
    }

    // Stage all 4096 points.
    for (int j = threadIdx.x; j < BQ_N; j += 512) {
        const float x = src[3 * j + 0];
        const float y = src[3 * j + 1];
        const float z = src[3 * j + 2];
        pts[j] = make_float4(x, y, z, sq_plain(x, y, z));
    }
    __syncthreads();

    uint64_t W[8] = {0, 0, 0, 0, 0, 0, 0, 0};
    int      F[8] = {0, 0, 0, 0, 0, 0, 0, 0};

    // Scan this wave's half: k in [half*32, half*32+32). Local early-exit
    // at found>=32 is exact (even half: first-32 complete; odd half: its
    // 33rd+ local matches can never rank in the global first 32).
    const int kbase = half << 5;
    #pragma unroll 1
    for (int c = 0; c < 16; ++c) {
        #pragma unroll
        for (int u = 0; u < 2; ++u) {
            const int k = kbase + (c << 1) + u;
            const float4 s = pts[(k << 6) + lane];
            #pragma unroll
            for (int j = 0; j < 8; ++j) {
                const float d2 = d2_mixed_s(qx[j], qy[j], qz[j], qw[j],
                                            s.x, s.y, s.z, s.w);
                const uint64_t bal = __ballot(d2 < BQ_R2);
                if (lane == k) W[j] = bal;
                F[j] += (int)__popcll(bal);
            }
        }
        bool all_done = true;
        #pragma unroll
        for (int j = 0; j < 8; ++j) all_done = all_done && (F[j] >= BQ_NS);
        if (all_done) break;   // wave-uniform
    }

    // Odd wave publishes its words (held in its lanes 32..63).
    if (half == 1) {
        #pragma unroll
        for (int j = 0; j < 8; ++j) {
            if (lane >= 32) xw[pair][j][lane - 32] = W[j];
        }
    }
    __syncthreads();

    // Even wave merges (lanes 0..31: own words; 32..63: odd's) and emits.
    if (half == 0) {
        #pragma unroll 1
        for (int j = 0; j < 8; ++j) {
            uint64_t word = W[j];
            if (lane >= 32) word = xw[pair][j][lane - 32];
            const int m = qbase + (pair << 3) + j;
            emit_query(outb + (size_t)m * BQ_NS, lane, word);
        }
    }
}

extern "C" void kernel_launch(void* const* d_in, const int* in_sizes, int n_in,
                              void* d_out, int out_size, void* d_ws, size_t ws_size,
                              hipStream_t stream)
{
    const float* xyz = (const float*)d_in[0];   // (8, 4096, 3) f32; d_in[1] unused
    int* out = (int*)d_out;                     // (8, 4096, 32) int32
    hipLaunchKernelGGL(ball_query_kernel, dim3(1024), dim3(512), 0, stream,
                       xyz, out);
}

// Round 15
// 89.586 us; speedup vs baseline: 1.3378x; 1.3378x over previous
//
#include <hip/hip_runtime.h>
#include <cstdint>

// Ball query: B=8, N=4096, radius=0.2, nsample=32. Queries == sources.
// Output int32 (B,N,32): first 32 in-radius indices ascending, padded with
// the first match.
//
// NUMERICS (LOCKED, R8-verified absmax=0): expansion form f32,
//   sq  = (x*x + y*y) + z*z              -- plain, no FMA
//   dot = fma(qz,sz, fma(qy,sy, qx*sx))  -- FMA, K ascending
//   d2  = (sqq + sqs) - (dot + dot)
//   match = d2 < 0.04f
// Inline asm (immune to -ffast-math). DO NOT CHANGE the op sequence.
//
// R15 perf: R14 proved branch-free 8-query rounds reach VALUBusy 67%, but
// always-compute-8 + half-split inflated work 4.5x (48us VALU). This round:
// NO half-split (it ~doubles scan depth: 78% of queries are within r of a
// face, so 32-of-M/2 in a half scans nearly as deep as 32-of-M in full);
// instead each wave bitonic-sorts its block's 64 queries by an analytic
// scan-length proxy (clipped-ball volume ~ local density) and takes 8
// SIMILAR queries -> max(group)/mean ~= 1.25, so branch-free rounds are
// near work-optimal. One uniform all-done check per 256-pt chunk.

#define BQ_N   4096
#define BQ_B   8
#define BQ_NS  32
#define BQ_R2  0.04f

__device__ __forceinline__ float sq_plain(float x, float y, float z) {
    float r, t;
    asm("v_mul_f32 %0, %2, %2\n\t"
        "v_mul_f32 %1, %3, %3\n\t"
        "v_add_f32 %0, %0, %1\n\t"
        "v_mul_f32 %1, %4, %4\n\t"
        "v_add_f32 %0, %0, %1"
        : "=&v"(r), "=&v"(t)
        : "v"(x), "v"(y), "v"(z));
    return r;
}

// Query operands in SGPRs (wave-uniform; 1 SGPR read per VALU op -- legal).
// Identical opcode sequence to the R8-verified version.
__device__ __forceinline__ float d2_mixed_s(float qx, float qy, float qz,
                                            float sqq,
                                            float sx, float sy, float sz,
                                            float sqs) {
    float r, t;
    asm("v_mul_f32 %0, %2, %5\n\t"     // qx*sx
        "v_fma_f32 %0, %3, %6, %0\n\t" // + qy*sy (fused)
        "v_fma_f32 %0, %4, %7, %0\n\t" // + qz*sz (fused) = dot
        "v_add_f32 %0, %0, %0\n\t"     // 2*dot (exact)
        "v_add_f32 %1, %8, %9\n\t"     // sqq + sqs
        "v_sub_f32 %0, %1, %0"         // d2
        : "=&v"(r), "=&v"(t)
        : "s"(qx), "s"(qy), "s"(qz), "v"(sx), "v"(sy), "v"(sz),
          "s"(sqq), "v"(sqs));
    return r;
}

__device__ __forceinline__ float rfl(float v) {
    return __int_as_float(__builtin_amdgcn_readfirstlane(__float_as_int(v)));
}

// 1D overlap fraction of the r-ball with [0,1] along one axis (t = dist/r,
// clamped): exact-enough analytic proxy for local match density. Perf-only.
__device__ __forceinline__ float gfun(float q) {
    float t = fminf(q, 1.0f - q) * 5.0f;   // dist-to-face / r
    t = fminf(t, 1.0f);
    return 0.5f + (0.75f - 0.25f * t * t) * t;
}

__device__ __forceinline__ void emit_query(int* orow, int lane, uint64_t word) {
    const int cnt = __popcll(word);
    int incl = cnt;
    #pragma unroll
    for (int off = 1; off < 64; off <<= 1) {
        const int t = __shfl_up(incl, off);
        if (lane >= off) incl += t;
    }
    const int pre   = incl - cnt;
    const int total = __shfl(incl, 63);

    int first;
    const uint64_t nz = __ballot(word != 0ull);
    if (nz == 0ull) {
        first = BQ_N;   // defensive; self-match makes this unreachable
    } else {
        const int fl = __builtin_ctzll(nz);
        const uint64_t fw = __shfl(word, fl);
        first = (fl << 6) + __builtin_ctzll(fw);
    }

    uint64_t w = word;
    int pos = pre;
    while (w != 0ull && pos < BQ_NS) {
        const int bit = __builtin_ctzll(w);
        orow[pos] = (lane << 6) + bit;
        w &= (w - 1);
        ++pos;
    }
    if (lane >= total && lane < BQ_NS) orow[lane] = first;  // padding
}

__global__ __launch_bounds__(512, 4)
void ball_query_kernel(const float* __restrict__ xyz, int* __restrict__ out)
{
    __shared__ float4 pts[BQ_N];   // 64 KiB -> 2 blocks/CU, 16 waves/CU

    const int b     = blockIdx.x >> 6;         // 64 blocks per batch
    const int qbase = (blockIdx.x & 63) << 6;  // 64 queries per block
    const float* __restrict__ src = xyz + (size_t)b * BQ_N * 3;
    const int lane = threadIdx.x & 63;
    const int wid  = threadIdx.x >> 6;         // 0..7
    int* __restrict__ outb = out + (size_t)(b * BQ_N) * BQ_NS;

    // ---- scan-length proxy for query (qbase+lane); sort 64 queries ----
    // (every wave computes the identical sort in-register; perf-only)
    unsigned long long v;
    {
        const int m = qbase + lane;
        const float x = src[3 * m + 0];
        const float y = src[3 * m + 1];
        const float z = src[3 * m + 2];
        const float key = gfun(x) * gfun(y) * gfun(z);  // ~ density
        v = ((unsigned long long)__float_as_uint(key) << 32) | (unsigned)lane;
    }
    #pragma unroll
    for (int k = 2; k <= 64; k <<= 1) {
        #pragma unroll
        for (int j = k >> 1; j > 0; j >>= 1) {
            const unsigned long long o = __shfl_xor(v, j);
            const bool up       = ((lane & k) == 0);
            const bool take_min = (((lane & j) == 0) == up);
            const bool less     = (v < o);
            v = (less == take_min) ? v : o;   // min or max of the pair
        }
    }
    int qlocal[8];
    #pragma unroll
    for (int j = 0; j < 8; ++j)
        qlocal[j] = (int)(__shfl(v, (wid << 3) + j) & 0xffffffffull) & 63;

    // ---- stage all 4096 points ----
    for (int j = threadIdx.x; j < BQ_N; j += 512) {
        const float x = src[3 * j + 0];
        const float y = src[3 * j + 1];
        const float z = src[3 * j + 2];
        pts[j] = make_float4(x, y, z, sq_plain(x, y, z));
    }
    __syncthreads();

    // Wave's 8 (similar-length) queries -> SGPRs.
    float qx[8], qy[8], qz[8], qw[8];
    #pragma unroll
    for (int j = 0; j < 8; ++j) {
        const float4 Qj = pts[qbase + qlocal[j]];   // broadcast read
        qx[j] = rfl(Qj.x); qy[j] = rfl(Qj.y);
        qz[j] = rfl(Qj.z); qw[j] = rfl(Qj.w);
    }

    uint64_t W[8] = {0, 0, 0, 0, 0, 0, 0, 0};
    int      F[8] = {0, 0, 0, 0, 0, 0, 0, 0};

    // Branch-free 8-query rounds; uniform all-done check per 256-pt chunk.
    #pragma unroll 1
    for (int c = 0; c < 16; ++c) {
        #pragma unroll
        for (int u = 0; u < 4; ++u) {
            const int k = (c << 2) + u;
            const float4 s = pts[(k << 6) + lane];
            #pragma unroll
            for (int j = 0; j < 8; ++j) {
                const float d2 = d2_mixed_s(qx[j], qy[j], qz[j], qw[j],
                                            s.x, s.y, s.z, s.w);
                const uint64_t bal = __ballot(d2 < BQ_R2);
                if (lane == k) W[j] = bal;
                F[j] += (int)__popcll(bal);
            }
        }
        bool done = true;
        #pragma unroll
        for (int j = 0; j < 8; ++j) done = done && (F[j] >= BQ_NS);
        if (done) break;   // wave-uniform
    }

    #pragma unroll 1
    for (int j = 0; j < 8; ++j) {
        const int m = qbase + qlocal[j];
        emit_query(outb + (size_t)m * BQ_NS, lane, W[j]);
    }
}

extern "C" void kernel_launch(void* const* d_in, const int* in_sizes, int n_in,
                              void* d_out, int out_size, void* d_ws, size_t ws_size,
                              hipStream_t stream)
{
    const float* xyz = (const float*)d_in[0];   // (8, 4096, 3) f32; d_in[1] unused
    int* out = (int*)d_out;                     // (8, 4096, 32) int32
    hipLaunchKernelGGL(ball_query_kernel, dim3(BQ_B * 64), dim3(512), 0, stream,
                       xyz, out);
}